// Round 6
// baseline (340.394 us; speedup 1.0000x reference)
//
#include <hip/hip_runtime.h>
#include <hip/hip_bf16.h>
#include <math.h>

// Problem constants
constexpr int kD  = 1024;
constexpr int kH1 = 4096;
constexpr int kO  = 1024;
constexpr int kE  = 8;
constexpr int kB  = 8192;

constexpr int BM   = 128;            // row-tile
constexpr int MAXT = kB / BM + kE;   // 72 row-tiles upper bound

typedef __attribute__((ext_vector_type(8))) short short8;
typedef __attribute__((ext_vector_type(4))) float f32x4;

__device__ __forceinline__ unsigned short f2bf(float f) {
  unsigned int u = __float_as_uint(f);
  u += 0x7fffu + ((u >> 16) & 1u);
  return (unsigned short)(u >> 16);
}
__device__ __forceinline__ float bf2f(unsigned short u) {
  return __uint_as_float(((unsigned int)u) << 16);
}

// tanh-form gelu (max |err| vs erf-gelu ~1e-3, << bf16 noise)
__device__ __forceinline__ float gelu_fast(float x) {
  float u = 0.7978845608028654f * (x + 0.044715f * x * x * x);
  float eu = __expf(2.0f * u);
  float th = 1.0f - 2.0f / (eu + 1.0f);
  return 0.5f * x * (1.0f + th);
}

// ---------------------------------------------------------------------------
// Setup: per-expert counts, permutation, 128-row tile table.
// tiles[t] = {expert, row_start (perm space), nrows, 0}
// ---------------------------------------------------------------------------
__global__ __launch_bounds__(256) void setup_kernel(const int* __restrict__ eid,
                                                    int* __restrict__ perm,
                                                    int* __restrict__ tiles) {
  __shared__ int cnt[kE];
  __shared__ int off[kE];
  __shared__ int cur[kE];
  int t = threadIdx.x;
  if (t < kE) { cnt[t] = 0; cur[t] = 0; }
  __syncthreads();
  for (int i = t; i < kB; i += 256) atomicAdd(&cnt[eid[i]], 1);
  __syncthreads();
  if (t == 0) {
    int o = 0, nt = 0;
    for (int e = 0; e < kE; ++e) {
      off[e] = o;
      int c = cnt[e];
      for (int r = 0; r < c; r += BM) {
        tiles[nt * 4 + 0] = e;
        tiles[nt * 4 + 1] = o + r;
        tiles[nt * 4 + 2] = (c - r < BM) ? (c - r) : BM;
        tiles[nt * 4 + 3] = 0;
        ++nt;
      }
      o += c;
    }
    for (; nt < MAXT; ++nt) {
      tiles[nt * 4 + 0] = 0; tiles[nt * 4 + 1] = 0;
      tiles[nt * 4 + 2] = 0; tiles[nt * 4 + 3] = 0;
    }
  }
  __syncthreads();
  for (int i = t; i < kB; i += 256) {
    int e = eid[i];
    int p = off[e] + atomicAdd(&cur[e], 1);
    perm[p] = i;
  }
}

// ---------------------------------------------------------------------------
// Gather x rows into perm order, fp32 -> bf16.  xg is [kB+256][kD] bf16.
// ---------------------------------------------------------------------------
__global__ __launch_bounds__(256) void gather_kernel(const float* __restrict__ x,
                                                     const int* __restrict__ perm,
                                                     unsigned short* __restrict__ xg) {
  int idx = blockIdx.x * 256 + threadIdx.x;
  int pos = idx >> 7;
  int c   = (idx & 127) << 3;
  int row = perm[pos];
  const float4* s = (const float4*)(x + (size_t)row * kD + c);
  float4 f0 = s[0], f1 = s[1];
  short8 v;
  v[0] = (short)f2bf(f0.x); v[1] = (short)f2bf(f0.y);
  v[2] = (short)f2bf(f0.z); v[3] = (short)f2bf(f0.w);
  v[4] = (short)f2bf(f1.x); v[5] = (short)f2bf(f1.y);
  v[6] = (short)f2bf(f1.z); v[7] = (short)f2bf(f1.w);
  *(short8*)(xg + (size_t)pos * kD + c) = v;
}

// ---------------------------------------------------------------------------
// Bulk fp32 -> bf16 convert (weights).
// ---------------------------------------------------------------------------
__global__ __launch_bounds__(256) void convert_kernel(const float* __restrict__ src,
                                                      unsigned short* __restrict__ dst,
                                                      int n8) {
  int stride = gridDim.x * 256;
  for (int i = blockIdx.x * 256 + threadIdx.x; i < n8; i += stride) {
    const float4* s = (const float4*)(src + (size_t)i * 8);
    float4 f0 = s[0], f1 = s[1];
    short8 v;
    v[0] = (short)f2bf(f0.x); v[1] = (short)f2bf(f0.y);
    v[2] = (short)f2bf(f0.z); v[3] = (short)f2bf(f0.w);
    v[4] = (short)f2bf(f1.x); v[5] = (short)f2bf(f1.y);
    v[6] = (short)f2bf(f1.z); v[7] = (short)f2bf(f1.w);
    *(short8*)(dst + (size_t)i * 8) = v;
  }
}

// ---------------------------------------------------------------------------
// 128x256 2-phase grouped GEMM.  C[m][n] = sum_k A[m][k]*B[e][n][k] (bf16).
// 512 thr = 8 waves, wave tile 64x64: r0=(w>>2)*64, frag cols j*64+(w&3)*16.
// BK=64; LDS slots per K-tile [A(16K), B0(16K), B1(16K)] = 48KB, dbuf 96KB.
// 6 load-issues/K-tile, staged 1 K-tile ahead (3 per phase); counted
// vmcnt(2)/(3); swizzle col ^= (row&7)<<3 on source + ds_read (rule 21).
// MODE 0: epilogue gelu->bf16 out_bf (h, perm space), stride N=4096.
// MODE 1: split-K half from pancol: half0 -> fp32 out_f scattered via perm
//         (partial, no bias); half1 -> bf16 out_bf (partial, perm space).
// ---------------------------------------------------------------------------
template <int KTOT, int KTILES, int N, int NPAN, int MODE>
__global__ __launch_bounds__(512, 2) void gemm2p_kernel(
    const unsigned short* __restrict__ Amat,
    const unsigned short* __restrict__ Bmat,
    const int* __restrict__ tiles,
    const int* __restrict__ perm,
    unsigned short* __restrict__ out_bf,
    float* __restrict__ out_f) {
  extern __shared__ unsigned short lds[];  // [2][3][8192]

  // XCD-chunked swizzle: 16-block chunks cover 4 ti x 4 pancols.
  constexpr int total = MAXT * NPAN;       // grid size (%8 == 0, %16 == 0)
  constexpr int cpx = total >> 3;
  constexpr int nchN = NPAN / 4;
  const int bid = blockIdx.x;
  const int id = (bid & 7) * cpx + (bid >> 3);
  const int chunk = id >> 4;
  const int a16 = id & 15;
  const int ti = (chunk / nchN) * 4 + (a16 & 3);
  const int pancol = (chunk % nchN) * 4 + (a16 >> 2);

  int n0, kb, half;
  if constexpr (MODE == 0) {
    n0 = pancol * 256; kb = 0; half = 0;
  } else {
    half = pancol >> 2; n0 = (pancol & 3) * 256; kb = half * (KTOT / 2);
  }

  const int e  = tiles[ti * 4 + 0];
  const int rs = tiles[ti * 4 + 1];
  const int nr = tiles[ti * 4 + 2];
  if (nr == 0) return;

  const int t = threadIdx.x;
  const int l = t & 63;
  const int w = t >> 6;
  const int r0 = (w >> 2) * 64;
  const int wc16 = (w & 3) * 16;

  const unsigned short* Bp = Bmat + (size_t)e * N * KTOT;

  // Per-lane swizzled LDS offsets (loop-invariant).
  int offA[4][2], offB[4][2];
#pragma unroll
  for (int mr = 0; mr < 4; ++mr)
#pragma unroll
    for (int ks = 0; ks < 2; ++ks) {
      int r = r0 + mr * 16 + (l & 15);
      offA[mr][ks] = r * 64 + ((ks * 32 + (l >> 4) * 8) ^ ((r & 7) << 3));
    }
#pragma unroll
  for (int j = 0; j < 4; ++j)
#pragma unroll
    for (int ks = 0; ks < 2; ++ks) {
      int rB = 64 * (j & 1) + wc16 + (l & 15);
      offB[j][ks] = (j >> 1) * 8192 + rB * 64 +
                    ((ks * 32 + (l >> 4) * 8) ^ ((rB & 7) << 3));
    }

  // One load-issue (8KB = 512thr x 16B).  idx: 0,1=A halves 2,3=B0 4,5=B1.
  auto stage = [&](int buf, int k0, int idx) {
    const int slot = idx >> 1, hf = idx & 1;
    int elem = (hf * 512 + t) * 8;
    int r = elem >> 6, cp = elem & 63;
    int cl = cp ^ ((r & 7) << 3);
    const unsigned short* src =
        (slot == 0) ? Amat + (size_t)(rs + r) * KTOT + k0 + cl
                    : Bp + (size_t)(n0 + (slot - 1) * 128 + r) * KTOT + k0 + cl;
    unsigned short* dst = lds + buf * 24576 + slot * 8192 + elem;
    __builtin_amdgcn_global_load_lds(
        (const __attribute__((address_space(1))) unsigned int*)src,
        (__attribute__((address_space(3))) unsigned int*)dst, 16, 0, 0);
  };

  short8 aF[4][2], bF[4][2];
  f32x4 acc[4][4] = {};   // [j][mr]

  auto readA = [&](int buf) {
    const unsigned short* base = lds + buf * 24576;
#pragma unroll
    for (int mr = 0; mr < 4; ++mr)
#pragma unroll
      for (int ks = 0; ks < 2; ++ks)
        aF[mr][ks] = *(const short8*)(base + offA[mr][ks]);
  };
  auto readB = [&](int buf, int jlo) {
    const unsigned short* base = lds + buf * 24576 + 8192;
#pragma unroll
    for (int j = 0; j < 2; ++j)
#pragma unroll
      for (int ks = 0; ks < 2; ++ks)
        bF[jlo + j][ks] = *(const short8*)(base + offB[jlo + j][ks]);
  };
  auto mfmaH = [&](int jlo) {
    __builtin_amdgcn_s_setprio(1);
#pragma unroll
    for (int j = 0; j < 2; ++j)
#pragma unroll
      for (int mr = 0; mr < 4; ++mr)
#pragma unroll
        for (int ks = 0; ks < 2; ++ks)
          acc[jlo + j][mr] = __builtin_amdgcn_mfma_f32_16x16x32_bf16(
              aF[mr][ks], bF[jlo + j][ks], acc[jlo + j][mr], 0, 0, 0);
    __builtin_amdgcn_s_setprio(0);
  };

  // Prologue: stage K-tile 0 (6 issues).
#pragma unroll
  for (int idx = 0; idx < 6; ++idx) stage(0, kb, idx);

  for (int kt = 0; kt < KTILES - 1; ++kt) {
    const int buf = kt & 1;
    const int nb = buf ^ 1;
    const int k0n = kb + (kt + 1) * 64;
    // ph0: needs A+B0 of kt (issues 0-3 retired -> vmcnt(2))
    asm volatile("s_waitcnt vmcnt(2)" ::: "memory");
    __builtin_amdgcn_s_barrier();
    readA(buf);
    readB(buf, 0);
    stage(nb, k0n, 0); stage(nb, k0n, 1); stage(nb, k0n, 2);
    __builtin_amdgcn_s_barrier();
    mfmaH(0);
    // ph1: needs B1 of kt (issues 4-5 retired; 3 newer outstanding -> vmcnt(3))
    asm volatile("s_waitcnt vmcnt(3)" ::: "memory");
    __builtin_amdgcn_s_barrier();
    readB(buf, 2);
    stage(nb, k0n, 3); stage(nb, k0n, 4); stage(nb, k0n, 5);
    __builtin_amdgcn_s_barrier();
    mfmaH(2);
  }
  // Last K-tile: no staging; ph1 must fully drain.
  {
    const int buf = (KTILES - 1) & 1;
    asm volatile("s_waitcnt vmcnt(2)" ::: "memory");
    __builtin_amdgcn_s_barrier();
    readA(buf);
    readB(buf, 0);
    __builtin_amdgcn_s_barrier();
    mfmaH(0);
    asm volatile("s_waitcnt vmcnt(0)" ::: "memory");
    __builtin_amdgcn_s_barrier();
    readB(buf, 2);
    __builtin_amdgcn_s_barrier();
    mfmaH(2);
  }

  // Epilogue.  D frag: row = r0 + mr*16 + (l>>4)*4 + rg ; col = j*64+wc16+(l&15)
  const int lr4 = (l >> 4) * 4;
  const int lc  = l & 15;
#pragma unroll
  for (int mr = 0; mr < 4; ++mr)
#pragma unroll
    for (int rg = 0; rg < 4; ++rg) {
      int row = r0 + mr * 16 + lr4 + rg;
      if (row < nr) {
        if constexpr (MODE == 0) {
          unsigned short* dst = out_bf + (size_t)(rs + row) * N + n0;
#pragma unroll
          for (int j = 0; j < 4; ++j)
            dst[j * 64 + wc16 + lc] = f2bf(gelu_fast(acc[j][mr][rg]));
        } else {
          if (half == 0) {
            float* dst = out_f + (size_t)perm[rs + row] * N + n0;
#pragma unroll
            for (int j = 0; j < 4; ++j)
              dst[j * 64 + wc16 + lc] = acc[j][mr][rg];
          } else {
            unsigned short* dst = out_bf + (size_t)(rs + row) * N + n0;
#pragma unroll
            for (int j = 0; j < 4; ++j)
              dst[j * 64 + wc16 + lc] = f2bf(acc[j][mr][rg]);
          }
        }
      }
    }
}

// ---------------------------------------------------------------------------
// Reduce: y[orig] = y[orig](=partial0) + partial1(bf16, perm space) + b2[e].
// ---------------------------------------------------------------------------
__global__ __launch_bounds__(256) void reduce_kernel(float* __restrict__ y,
                                                     const unsigned short* __restrict__ part,
                                                     const int* __restrict__ perm,
                                                     const int* __restrict__ eid,
                                                     const float* __restrict__ b2) {
  int idx = blockIdx.x * 256 + threadIdx.x;
  int p = idx >> 7;
  int c = (idx & 127) << 3;
  int orig = perm[p];
  int e = eid[orig];
  float* yp = y + (size_t)orig * kO + c;
  short8 pv = *(const short8*)(part + (size_t)p * kO + c);
  const float* bp = b2 + (size_t)e * kO + c;
  float4 y0 = *(float4*)yp, y1 = *(float4*)(yp + 4);
  float4 b0 = *(const float4*)bp, b1 = *(const float4*)(bp + 4);
  y0.x += bf2f((unsigned short)pv[0]) + b0.x;
  y0.y += bf2f((unsigned short)pv[1]) + b0.y;
  y0.z += bf2f((unsigned short)pv[2]) + b0.z;
  y0.w += bf2f((unsigned short)pv[3]) + b0.w;
  y1.x += bf2f((unsigned short)pv[4]) + b1.x;
  y1.y += bf2f((unsigned short)pv[5]) + b1.y;
  y1.z += bf2f((unsigned short)pv[6]) + b1.z;
  y1.w += bf2f((unsigned short)pv[7]) + b1.w;
  *(float4*)yp = y0;
  *(float4*)(yp + 4) = y1;
}

// ---------------------------------------------------------------------------
extern "C" void kernel_launch(void* const* d_in, const int* in_sizes, int n_in,
                              void* d_out, int out_size, void* d_ws, size_t ws_size,
                              hipStream_t stream) {
  const float* x  = (const float*)d_in[0];
  const int*  eid = (const int*)d_in[1];
  const float* W1 = (const float*)d_in[2];
  const float* W2 = (const float*)d_in[3];
  const float* b2 = (const float*)d_in[4];
  float* y = (float*)d_out;

  char* ws = (char*)d_ws;
  int* perm  = (int*)ws;                                   // 32KB
  int* tiles = (int*)(ws + 32768);
  unsigned short* xg = (unsigned short*)(ws + 36864);      // [kB+256][kD] bf16
  size_t xg_bytes = (size_t)(kB + 256) * kD * 2;           // 17,301,504
  unsigned short* h  = (unsigned short*)(ws + 36864 + xg_bytes);  // [kB+256][kH1]
  size_t h_bytes = (size_t)(kB + 256) * kH1 * 2;           // 69,206,016
  unsigned short* Wb = (unsigned short*)(ws + 36864 + xg_bytes + h_bytes);  // 64MB

  constexpr int kWelems8 = kE * kH1 * kD / 8;

  auto g1 = gemm2p_kernel<kD, 16, kH1, 16, 0>;
  auto g2 = gemm2p_kernel<kH1, 32, kO, 8, 1>;
  hipFuncSetAttribute((const void*)g1, hipFuncAttributeMaxDynamicSharedMemorySize, 98304);
  hipFuncSetAttribute((const void*)g2, hipFuncAttributeMaxDynamicSharedMemorySize, 98304);

  setup_kernel<<<1, 256, 0, stream>>>(eid, perm, tiles);
  gather_kernel<<<(kB * kD / 8) / 256, 256, 0, stream>>>(x, perm, xg);

  // GEMM1: h = gelu(xg @ W1[e]^T)
  convert_kernel<<<2048, 256, 0, stream>>>(W1, Wb, kWelems8);
  g1<<<MAXT * 16, 512, 98304, stream>>>(xg, Wb, tiles, perm, h, nullptr);

  // GEMM2 split-K=2: half0 -> y (fp32, scattered), half1 -> xg region (bf16).
  convert_kernel<<<2048, 256, 0, stream>>>(W2, Wb, kWelems8);
  g2<<<MAXT * 8, 512, 98304, stream>>>(h, Wb, tiles, perm, xg, y);

  // y += partial1 + b2
  reduce_kernel<<<(kB * kO / 8) / 256, 256, 0, stream>>>(y, xg, perm, eid, b2);
}